// Round 9
// baseline (426.291 us; speedup 1.0000x reference)
//
#include <hip/hip_runtime.h>
#include <math.h>

// Problem constants (fixed by setup_inputs)
#define LQ    17821
#define MROWS 35642     // Lq * B
#define KD    256

typedef __attribute__((ext_vector_type(8))) short bf16x8;   // 8 bf16 = 4 VGPRs
typedef __attribute__((ext_vector_type(4))) float f32x4;
typedef unsigned int u32;

__device__ __forceinline__ short f2bf(float f) {
  union { float f; unsigned u; } c; c.f = f;
  unsigned u = c.u;
  return (short)((u + 0x7fffu + ((u >> 16) & 1u)) >> 16);   // RNE
}
__device__ __forceinline__ float bf2f(short s) {
  union { unsigned u; float f; } c;
  c.u = ((unsigned)(unsigned short)s) << 16;
  return c.f;
}

// async global->LDS, 16 B per lane: LDS dest = wave-uniform base + lane*16
__device__ __forceinline__ void gld_lds16(const short* g, short* l) {
  __builtin_amdgcn_global_load_lds(
      (const __attribute__((address_space(1))) u32*)g,
      (__attribute__((address_space(3))) u32*)l, 16, 0, 0);
}

// s_waitcnt immediates (gfx9 encoding: vm[3:0]|[15:14], exp[6:4], lgkm[11:8])
#define WAIT_VM4   { __builtin_amdgcn_s_waitcnt(0x0F74); asm volatile("" ::: "memory"); }
#define WAIT_VM0   { __builtin_amdgcn_s_waitcnt(0x0F70); asm volatile("" ::: "memory"); }
#define WAIT_LGKM0 { __builtin_amdgcn_s_waitcnt(0xC07F); asm volatile("" ::: "memory"); }
#define BARRIER    { asm volatile("" ::: "memory"); __builtin_amdgcn_s_barrier(); asm volatile("" ::: "memory"); }

// ---------------------------------------------------------------------------
// prep: y=0 -> query fp32->bf16; y=1 -> value fp32->bf16;
//       y=2 -> all 4 W^T bf16 transposes + fused bias (first ~898 blocks).
// wT layout: [0,65536) Wv^T | [65536,131072) Woff^T | [131072,163840) Wat^T |
//            [163840,229376) Wout^T   (each W^T is (N x 256) row-major)
// ---------------------------------------------------------------------------
__global__ __launch_bounds__(256) void prep(
    const float* __restrict__ query, const float* __restrict__ value,
    const float* __restrict__ Wv, const float* __restrict__ Woff,
    const float* __restrict__ Wat, const float* __restrict__ Wout,
    const float* __restrict__ boff, const float* __restrict__ bat,
    short* __restrict__ qb, short* __restrict__ vb,
    short* __restrict__ wT, float* __restrict__ fbias)
{
  const int y = blockIdx.y;
  if (y < 2) {
    const float* s = y ? value : query;
    short* d = y ? vb : qb;
    int i = (blockIdx.x * 256 + threadIdx.x) * 4;
    if (i < MROWS * KD) {
      float4 x = *(const float4*)(s + i);
      short4 o;
      o.x = f2bf(x.x); o.y = f2bf(x.y); o.z = f2bf(x.z); o.w = f2bf(x.w);
      *(short4*)(d + i) = o;
    }
    return;
  }
  int idx = blockIdx.x * 256 + threadIdx.x;
  if (idx < 229376) {
    const float* W; int base, N;
    if (idx < 65536)       { W = Wv;   base = 0;      N = 256; }
    else if (idx < 131072) { W = Woff; base = 65536;  N = 256; }
    else if (idx < 163840) { W = Wat;  base = 131072; N = 128; }
    else                   { W = Wout; base = 163840; N = 256; }
    int local = idx - base;
    int n = local >> 8, k = local & 255;
    wT[idx] = f2bf(W[k * N + n]);
  } else if (idx < 229376 + 384) {
    int j = idx - 229376;
    fbias[j] = (j < 256) ? boff[j] : bat[j - 256];
  }
}

// ---------------------------------------------------------------------------
// Pipelined bf16 MFMA GEMM -- R9: exact R4 structure (BK=32, proven fastest)
// plus a `gymod` parameter for this round's MEASUREMENT PROBE.
//
// PROBE (this round only): gemm1 launched with gridDim.y=20, gymod=5 and
// gemm2 with gridDim.y=8, gymod=2 -> every output stripe computed 4x with
// IDENTICAL values (kernels are pure functions; duplicate concurrent writes
// of identical bytes are race-free). Purpose: (1) push the GEMM dispatches
// above msda's 91 us so they appear in rocprof top-5 WITH counters for the
// first time; (2) dur_us - 280.5 = 3*(gemm1+gemm2) decomposes the invariant
// ~190 us non-msda remainder into kernel time vs harness overhead.
//
// 128x128 tile, 256 thr = 4 waves (64x64 each as 4x4 16x16 tiles), BK=32,
// K=256 -> 8 tiles. 2-deep LDS double-buffer fed by global_load_lds w=16;
// K-loop waits vmcnt(4) (tile t landed, t+1 IN FLIGHT) + raw s_barrier;
// second barrier per iter is lgkm-only. Pure-gld staging (R7 lesson: never
// mix plain loads into the hand-counted vmcnt FIFO).
// LAUNCH_BOUNDS: plain (256) (rounds 2-5: min-waves clauses cause spill).
// ---------------------------------------------------------------------------
template<bool O1BF>
__global__ __launch_bounds__(256) void gemm_pipe(
    const short* __restrict__ A0, const short* __restrict__ A1,
    const short* __restrict__ Bt0, const short* __restrict__ Bt1,
    const float* __restrict__ bias0, const float* __restrict__ bias1,
    short* __restrict__ out0, void* __restrict__ out1v,
    int N1, int gymod, int gybase)
{
  __shared__ short As[2 * 128 * 32];   // 16 KB (2 buffers)
  __shared__ short Bs[2 * 128 * 32];   // 16 KB

  const int tid = threadIdx.x;
  const int gy = (blockIdx.y % gymod) + gybase;
  const bool sel0 = gy < 2;
  const short* A = sel0 ? A0 : A1;
  const short* Bt = sel0 ? Bt0 : Bt1;
  const float* bias = sel0 ? bias0 : bias1;
  const int bn = (sel0 ? gy : gy - 2) * 128;
  const int bm = blockIdx.x * 128;

  const int wv = tid >> 6;
  const int lane = tid & 63;

  // staging: wave wv stages rows [wv*32, wv*32+32) of A and B, two 16-row
  // segments each; lane covers (row = lane/4, kseg = lane%4)
  const int srow = lane >> 2;
  const int skel = (lane & 3) * 8;
  const int rA0 = min(bm + wv * 32 + srow, MROWS - 1);       // clamp tail
  const int rA1 = min(bm + wv * 32 + 16 + srow, MROWS - 1);
  const short* gA0 = A + (size_t)rA0 * KD + skel;
  const short* gA1 = A + (size_t)rA1 * KD + skel;
  const short* gB0 = Bt + (size_t)(bn + wv * 32 + srow) * KD + skel;
  const short* gB1 = Bt + (size_t)(bn + wv * 32 + 16 + srow) * KD + skel;
  short* lA0 = &As[(wv * 32) * 32];         // wave-uniform LDS bases
  short* lA1 = &As[(wv * 32 + 16) * 32];
  short* lB0 = &Bs[(wv * 32) * 32];
  short* lB1 = &Bs[(wv * 32 + 16) * 32];

#define ISSUE(t, buf)                          \
  {                                            \
    gld_lds16(gA0 + (t) * 32, lA0 + (buf) * 4096); \
    gld_lds16(gA1 + (t) * 32, lA1 + (buf) * 4096); \
    gld_lds16(gB0 + (t) * 32, lB0 + (buf) * 4096); \
    gld_lds16(gB1 + (t) * 32, lB1 + (buf) * 4096); \
  }

  const int wm = (wv & 1) * 64;
  const int wn = (wv >> 1) * 64;
  const int ln = lane & 15;
  const int lq = lane >> 4;

  f32x4 acc[4][4];
#pragma unroll
  for (int i = 0; i < 4; ++i)
#pragma unroll
    for (int j = 0; j < 4; ++j) acc[i][j] = (f32x4){0.f, 0.f, 0.f, 0.f};

  ISSUE(0, 0);
  ISSUE(1, 1);

#pragma unroll
  for (int t = 0; t < 8; ++t) {
    const int buf = t & 1;
    // tile t landed; tile t+1 (if any) stays in flight
    if (t < 7) { WAIT_VM4; } else { WAIT_VM0; }
    BARRIER;

    bf16x8 af[4], bfm[4];
#pragma unroll
    for (int i = 0; i < 4; ++i)
      af[i] = *(const bf16x8*)&As[buf * 4096 + (wm + i * 16 + ln) * 32 + lq * 8];
#pragma unroll
    for (int j = 0; j < 4; ++j)
      bfm[j] = *(const bf16x8*)&Bs[buf * 4096 + (wn + j * 16 + ln) * 32 + lq * 8];

    // all waves done reading this buffer before tile t+2 overwrites it
    WAIT_LGKM0;
    BARRIER;
    if (t + 2 < 8) ISSUE(t + 2, buf);

#pragma unroll
    for (int i = 0; i < 4; ++i)
#pragma unroll
      for (int j = 0; j < 4; ++j)
        acc[i][j] = __builtin_amdgcn_mfma_f32_16x16x32_bf16(af[i], bfm[j], acc[i][j], 0, 0, 0);
  }
#undef ISSUE

  // epilogue: C/D layout col=lane&15, row=(lane>>4)*4+reg
  const int N = sel0 ? 256 : N1;
#pragma unroll
  for (int j = 0; j < 4; ++j) {
    const int col = bn + wn + j * 16 + ln;
    const float bb = bias[col];
#pragma unroll
    for (int i = 0; i < 4; ++i) {
      const int row0 = bm + wm + i * 16 + lq * 4;
#pragma unroll
      for (int r = 0; r < 4; ++r) {
        const int row = row0 + r;
        if (row < MROWS) {
          float v = acc[i][j][r] + bb;
          if (sel0)
            out0[(size_t)row * 256 + col] = f2bf(v);
          else if (O1BF)
            ((short*)out1v)[(size_t)row * N + col] = f2bf(v);
          else
            ((float*)out1v)[(size_t)row * N + col] = v;
        }
      }
    }
  }
}

// ---------------------------------------------------------------------------
// Deformable sampling, two-phase, bf16 vproj + bf16 oa.  (UNCHANGED -- at its
// random-line request-throughput floor, 91 us; see rounds 0-5 notes.)
// HARD-WON CONFIG NOTES (rounds 0-5):
//  - NO min-waves clause in __launch_bounds__ (spill trap).
//  - No explicit software pipeline (spill trap).
//  - Occupancy beyond ~13 waves/CU does not help (line-throughput bound).
// vproj: (Lin*B, 256) bf16 rows (pix*B + b), cols h*32+d
// oa: fused bf16 (MROWS, 384): [0,256) offsets, [256,384) attn logits
// ---------------------------------------------------------------------------
__global__ __launch_bounds__(256) void msda_sample(
    const short* __restrict__ vproj, const short* __restrict__ oa,
    const float* __restrict__ refp, short* __restrict__ out)
{
  static constexpr int LVL_H[4] = {100, 50, 25, 13};
  static constexpr int LVL_W[4] = {134, 67, 34, 17};
  static constexpr int LVL_S[4] = {0, 13400, 16750, 17600};

  __shared__ uint4 s_pk[8 * 8 * 17];   // 17,408 B

  const int tid = threadIdx.x;
  const int m0 = blockIdx.x * 8;

  // ---------------- phase 1 ----------------
#pragma unroll
  for (int it = 0; it < 4; ++it) {
    int w = tid + it * 256;
    int mr = w >> 7;
    int rest = w & 127;
    int h = rest >> 4;
    int lp = rest & 15;
    int l = lp >> 2;
    int p = lp & 3;
    int m = m0 + mr;
    if (m < MROWS) {
      int b = m & 1, q = m >> 1;
      const int Hl = LVL_H[l], Wl = LVL_W[l], Sl = LVL_S[l];
      const float fW = (float)Wl, fH = (float)Hl;

      short4 a4 = *(const short4*)(oa + (size_t)m * 384 + 256 + h * 16 + l * 4);
      float a0 = bf2f(a4.x), a1 = bf2f(a4.y), a2 = bf2f(a4.z), a3 = bf2f(a4.w);
      float mx = fmaxf(fmaxf(a0, a1), fmaxf(a2, a3));
      a0 = __expf(a0 - mx); a1 = __expf(a1 - mx);
      a2 = __expf(a2 - mx); a3 = __expf(a3 - mx);
      float sel = (p == 0) ? a0 : (p == 1) ? a1 : (p == 2) ? a2 : a3;
      float aw = sel / (a0 + a1 + a2 + a3);

      const short* oPtr = oa + (size_t)m * 384 + h * 32 + l * 8 + p * 2;
      float ox = bf2f(oPtr[0]), oy = bf2f(oPtr[1]);
      const float* rPtr = refp + ((size_t)b * LQ + q) * 8 + l * 2;
      float rx = rPtr[0], ry = rPtr[1];

      float x = (rx + ox / fW) * fW - 0.5f;
      float y = (ry + oy / fH) * fH - 0.5f;
      float x0f = floorf(x), y0f = floorf(y);
      float dx = x - x0f, dy = y - y0f;
      int x0 = (int)x0f, y0 = (int)y0f;
      int x1 = x0 + 1, y1 = y0 + 1;

      float w00 = (1.f - dx) * (1.f - dy) * aw;
      float w10 = dx * (1.f - dy) * aw;
      float w01 = (1.f - dx) * dy * aw;
      float w11 = dx * dy * aw;

      bool vx0 = (x0 >= 0) & (x0 < Wl);
      bool vx1 = (x1 >= 0) & (x1 < Wl);
      bool vy0 = (y0 >= 0) & (y0 < Hl);
      bool vy1 = (y1 >= 0) & (y1 < Hl);
      int cx0 = min(max(x0, 0), Wl - 1);
      int cx1 = min(max(x1, 0), Wl - 1);
      int cy0 = min(max(y0, 0), Hl - 1);
      int cy1 = min(max(y1, 0), Hl - 1);

      int r0 = Sl + cy0 * Wl;
      int r1 = Sl + cy1 * Wl;

      float f00 = (vy0 & vx0) ? w00 : 0.f;
      float f10 = (vy0 & vx1) ? w10 : 0.f;
      float f01 = (vy1 & vx0) ? w01 : 0.f;
      float f11 = (vy1 & vx1) ? w11 : 0.f;
      u32 pk0 = (u32)((r0 + cx0) * 2 + b) |
                ((u32)__builtin_bit_cast(unsigned short, (_Float16)f00) << 16);
      u32 pk1 = (u32)((r0 + cx1) * 2 + b) |
                ((u32)__builtin_bit_cast(unsigned short, (_Float16)f10) << 16);
      u32 pk2 = (u32)((r1 + cx0) * 2 + b) |
                ((u32)__builtin_bit_cast(unsigned short, (_Float16)f01) << 16);
      u32 pk3 = (u32)((r1 + cx1) * 2 + b) |
                ((u32)__builtin_bit_cast(unsigned short, (_Float16)f11) << 16);
      int e = (mr * 8 + h) * 17 + lp;
      s_pk[e] = make_uint4(pk0, pk1, pk2, pk3);
    }
  }
  __syncthreads();

  // ---------------- phase 2 ----------------
  const int mr = tid >> 5;
  const int t = tid & 31;
  const int h = t >> 2;
  const int dq = t & 3;
  const int m = m0 + mr;
  if (m >= MROWS) return;

  const int laneOff = h * 32 + dq * 8;          // bf16 element offset
  const int ebase = (mr * 8 + h) * 17;
  const short* vp = vproj + laneOff;

  float acc[8];
#pragma unroll
  for (int e = 0; e < 8; ++e) acc[e] = 0.f;

#pragma unroll 4
  for (int lp = 0; lp < 16; ++lp) {
    uint4 pk = s_pk[ebase + lp];
    bf16x8 u00 = *(const bf16x8*)(vp + ((int)(pk.x & 0xFFFFu) << 8));
    bf16x8 u10 = *(const bf16x8*)(vp + ((int)(pk.y & 0xFFFFu) << 8));
    bf16x8 u01 = *(const bf16x8*)(vp + ((int)(pk.z & 0xFFFFu) << 8));
    bf16x8 u11 = *(const bf16x8*)(vp + ((int)(pk.w & 0xFFFFu) << 8));
    float w0 = (float)__builtin_bit_cast(_Float16, (unsigned short)(pk.x >> 16));
    float w1 = (float)__builtin_bit_cast(_Float16, (unsigned short)(pk.y >> 16));
    float w2 = (float)__builtin_bit_cast(_Float16, (unsigned short)(pk.z >> 16));
    float w3 = (float)__builtin_bit_cast(_Float16, (unsigned short)(pk.w >> 16));
#pragma unroll
    for (int e = 0; e < 8; ++e) {
      acc[e] = fmaf(w0, bf2f(u00[e]), acc[e]);
      acc[e] = fmaf(w1, bf2f(u10[e]), acc[e]);
      acc[e] = fmaf(w2, bf2f(u01[e]), acc[e]);
      acc[e] = fmaf(w3, bf2f(u11[e]), acc[e]);
    }
  }

  bf16x8 o;
#pragma unroll
  for (int e = 0; e < 8; ++e) o[e] = f2bf(acc[e]);
  *(bf16x8*)(out + (size_t)m * 256 + laneOff) = o;
}

// ---------------------------------------------------------------------------
extern "C" void kernel_launch(void* const* d_in, const int* in_sizes, int n_in,
                              void* d_out, int out_size, void* d_ws, size_t ws_size,
                              hipStream_t stream)
{
  const float* query = (const float*)d_in[0];   // (Lq, B, 256)
  const float* value = (const float*)d_in[1];   // (Lin, B, 256)
  const float* refp  = (const float*)d_in[2];   // (B, Lq, 4, 2)
  // d_in[3] = spatial_shapes (constant, hardcoded)
  const float* Wv   = (const float*)d_in[4];
  const float* bv   = (const float*)d_in[5];
  const float* Woff = (const float*)d_in[6];
  const float* boff = (const float*)d_in[7];
  const float* Wat  = (const float*)d_in[8];
  const float* bat  = (const float*)d_in[9];
  const float* Wout = (const float*)d_in[10];
  const float* bout = (const float*)d_in[11];
  float* out = (float*)d_out;

  const size_t NELT = (size_t)MROWS * 256;      // 9,124,352
  short* wT    = (short*)d_ws;                  // 229,376 bf16 (4 W^T)
  float* fbias = (float*)(wT + 229376);         // 384 fp32 (boff|bat)
  short* qb    = (short*)(fbias + 384);         // NELT bf16
  short* vb    = qb + NELT;                     // NELT bf16 (reused as accb)
  short* vproj = vb + NELT;                     // NELT bf16
  short* oa    = vproj + NELT;                  // MROWS*384 bf16
  short* accb  = vb;                            // alias (vb dead after GEMM)

  dim3 blk(256, 1, 1);
  int gm = (MROWS + 127) / 128;   // 279

  prep<<<dim3(8911, 3), blk, 0, stream>>>(
      query, value, Wv, Woff, Wat, Wout, boff, bat, qb, vb, wT, fbias);

  // MEASUREMENT PROBE (this round): gy doubled 4x via gymod -- every output
  // stripe computed 4 times with identical values (idempotent). Makes the
  // GEMM dispatches visible in rocprof top-5 and decomposes the remainder:
  // dur_us - 280.5 ~= 3*(gemm1+gemm2).
  gemm_pipe<true><<<dim3(gm, 20), blk, 0, stream>>>(
      vb, qb, wT, wT + 65536, bv, fbias, vproj, oa, 384, 5, 0);

  msda_sample<<<dim3((MROWS + 7) / 8), blk, 0, stream>>>(vproj, oa, refp, accb);

  gemm_pipe<false><<<dim3(gm, 8), blk, 0, stream>>>(
      accb, accb, wT + 163840, wT + 163840, bout, bout, nullptr, out, 256, 2, 2);
}

// Round 10
// 290.818 us; speedup vs baseline: 1.4658x; 1.4658x over previous
//
#include <hip/hip_runtime.h>
#include <math.h>

// Problem constants (fixed by setup_inputs)
#define LQ    17821
#define MROWS 35642     // Lq * B
#define KD    256

typedef __attribute__((ext_vector_type(8))) short bf16x8;   // 8 bf16 = 4 VGPRs
typedef __attribute__((ext_vector_type(4))) float f32x4;
typedef unsigned int u32;

__device__ __forceinline__ short f2bf(float f) {
  union { float f; unsigned u; } c; c.f = f;
  unsigned u = c.u;
  return (short)((u + 0x7fffu + ((u >> 16) & 1u)) >> 16);   // RNE
}
__device__ __forceinline__ float bf2f(short s) {
  union { unsigned u; float f; } c;
  c.u = ((unsigned)(unsigned short)s) << 16;
  return c.f;
}

// async global->LDS, 16 B per lane: LDS dest = wave-uniform base + lane*16
__device__ __forceinline__ void gld_lds16(const short* g, short* l) {
  __builtin_amdgcn_global_load_lds(
      (const __attribute__((address_space(1))) u32*)g,
      (__attribute__((address_space(3))) u32*)l, 16, 0, 0);
}

// s_waitcnt immediates (gfx9 encoding: vm[3:0]|[15:14], exp[6:4], lgkm[11:8])
#define WAIT_VM4   { __builtin_amdgcn_s_waitcnt(0x0F74); asm volatile("" ::: "memory"); }
#define WAIT_VM2   { __builtin_amdgcn_s_waitcnt(0x0F72); asm volatile("" ::: "memory"); }
#define WAIT_VM0   { __builtin_amdgcn_s_waitcnt(0x0F70); asm volatile("" ::: "memory"); }
#define WAIT_LGKM0 { __builtin_amdgcn_s_waitcnt(0xC07F); asm volatile("" ::: "memory"); }
#define BARRIER    { asm volatile("" ::: "memory"); __builtin_amdgcn_s_barrier(); asm volatile("" ::: "memory"); }

// ---------------------------------------------------------------------------
// prep_w: W^T bf16 transposes + fused bias only (898 blocks; the q/v
// conversion is fused into gemm_fused_in's A-staging -- R9 probe showed the
// old gemm1 re-read its A panel once per 128-wide stripe, 91 MB redundant).
// wT layout: [0,65536) Wv^T | [65536,131072) Woff^T | [131072,163840) Wat^T |
//            [163840,229376) Wout^T   (each W^T is (N x 256) row-major)
// NOTE: Woff^T || Wat^T are contiguous -> stream1's 384-wide B panel.
// ---------------------------------------------------------------------------
__global__ __launch_bounds__(256) void prep_w(
    const float* __restrict__ Wv, const float* __restrict__ Woff,
    const float* __restrict__ Wat, const float* __restrict__ Wout,
    const float* __restrict__ boff, const float* __restrict__ bat,
    short* __restrict__ wT, float* __restrict__ fbias)
{
  int idx = blockIdx.x * 256 + threadIdx.x;
  if (idx < 229376) {
    const float* W; int base, N;
    if (idx < 65536)       { W = Wv;   base = 0;      N = 256; }
    else if (idx < 131072) { W = Woff; base = 65536;  N = 256; }
    else if (idx < 163840) { W = Wat;  base = 131072; N = 128; }
    else                   { W = Wout; base = 163840; N = 256; }
    int local = idx - base;
    int n = local >> 8, k = local & 255;
    wT[idx] = f2bf(W[k * N + n]);
  } else if (idx < 229376 + 384) {
    int j = idx - 229376;
    fbias[j] = (j < 256) ? boff[j] : bat[j - 256];
  }
}

// ---------------------------------------------------------------------------
// R10: fused input GEMM. R9-probe counters (MfmaUtil 10, VALU 14, Occ 31,
// HBM 36 -- NOTHING saturated) + stripe-re-read arithmetic (5 x 18.25 MB of
// redundant A fetch) say: load A once, reuse across all N-stripes.
//
// Block (bx, s): stages its 128-row A panel ONCE -- fp32 loads + RNE cvt
// (bit-identical to the old prep) into a 64 KB LDS panel covering K=256 --
// then loops bn over all stripes (s=0: A=value, N=256 -> vproj; s=1:
// A=query, N=384 -> oa), streaming only B (wT, 448 KB, L2-resident) through
// a 16 KB double-buffer with the R4 counted-vmcnt discipline.
//
// vmcnt purity (R7 lesson): A's plain fp32 loads are all CONSUMED (compiler
// waits before cvt) before the staging barrier, so the main loop's VM FIFO
// holds only B glds (2/tile; entry WAIT_VM2) plus epilogue stores, which the
// counted wait conservatively drains between bn-iters. No mixed counting.
//
// A-LDS swizzle: [128][256] bf16, 32 x 16B slots/row; phys = (s&16)|((s^row)&15).
// Fragment rows have row&15 == ln, so reads use the same involution ->
// 16 lanes hit 16 distinct slots -> 2-way (free). Write side is ds_write_b128
// (we control the address; no global_load_lds on A), same involution.
// B keeps the R4 linear layout (its ~5% conflict cost, measured R9, is minor).
// MFMA k-order identical to R4 -> bit-identical output.
// LDS = 64+16 = 80 KB -> 2 blocks/CU.
// LAUNCH_BOUNDS: plain (256) (rounds 2-5: min-waves clauses cause spill).
// ---------------------------------------------------------------------------
__global__ __launch_bounds__(256) void gemm_fused_in(
    const float* __restrict__ value, const float* __restrict__ query,
    const short* __restrict__ wT, const float* __restrict__ bv,
    const float* __restrict__ fbias,
    short* __restrict__ vproj, short* __restrict__ oa)
{
  __shared__ short As[128 * 256];      // 64 KB, swizzled 16B slots
  __shared__ short Bs[2 * 128 * 32];   // 16 KB double buffer

  const int tid = threadIdx.x;
  const int s1 = blockIdx.y;           // 0: value->vproj, 1: query->oa
  const float* Af = s1 ? query : value;
  const short* Bt = s1 ? (wT + 65536) : wT;   // Woff^T||Wat^T contiguous
  const float* bias = s1 ? fbias : bv;
  const int NB = s1 ? 3 : 2;           // 128-wide stripes
  const int NW = s1 ? 384 : 256;       // output row width
  short* outp = s1 ? oa : vproj;
  const int bm = blockIdx.x * 128;

  // ---- A stage (once per block): fp32 -> bf16 RNE -> swizzled LDS ----
  // chunk c = tid + k*256 in [0,4096): row = c>>5, logical slot s = c&31.
#pragma unroll 4
  for (int k = 0; k < 16; ++k) {
    int c = tid + k * 256;
    int row = c >> 5, s = c & 31;
    int gr = min(bm + row, MROWS - 1);                 // clamp tail
    const float* src = Af + (size_t)gr * KD + s * 8;
    float4 x0 = *(const float4*)src;
    float4 x1 = *(const float4*)(src + 4);
    bf16x8 w;
    w[0] = f2bf(x0.x); w[1] = f2bf(x0.y); w[2] = f2bf(x0.z); w[3] = f2bf(x0.w);
    w[4] = f2bf(x1.x); w[5] = f2bf(x1.y); w[6] = f2bf(x1.z); w[7] = f2bf(x1.w);
    int ps = (s & 16) | ((s ^ row) & 15);
    *(bf16x8*)&As[row * 256 + ps * 8] = w;
  }
  __syncthreads();   // all A writes visible; all plain loads consumed

  const int wv = tid >> 6;
  const int lane = tid & 63;
  const int srow = lane >> 2;
  const int skel = (lane & 3) * 8;
  short* lB0 = &Bs[(wv * 32) * 32];          // wave-uniform LDS bases
  short* lB1 = &Bs[(wv * 32 + 16) * 32];

  const int wm = (wv & 1) * 64;
  const int wn = (wv >> 1) * 64;
  const int ln = lane & 15;
  const int lq = lane >> 4;

#define ISSUEB(t, buf)                              \
  {                                                 \
    gld_lds16(gB0 + (t) * 32, lB0 + (buf) * 4096);  \
    gld_lds16(gB1 + (t) * 32, lB1 + (buf) * 4096);  \
  }

  for (int bnI = 0; bnI < NB; ++bnI) {
    const int bn = bnI * 128;
    const short* gB0 = Bt + (size_t)(bn + wv * 32 + srow) * KD + skel;
    const short* gB1 = gB0 + (size_t)16 * KD;

    f32x4 acc[4][4];
#pragma unroll
    for (int i = 0; i < 4; ++i)
#pragma unroll
      for (int j = 0; j < 4; ++j) acc[i][j] = (f32x4){0.f, 0.f, 0.f, 0.f};

    ISSUEB(0, 0);
    ISSUEB(1, 1);

#pragma unroll
    for (int t = 0; t < 8; ++t) {
      const int buf = t & 1;
      // B(t) landed; B(t+1) stays in flight (stores from prior epilogue
      // are older in the FIFO and get drained too -- conservative, correct)
      if (t < 7) { WAIT_VM2; } else { WAIT_VM0; }
      BARRIER;

      bf16x8 af[4], bfm[4];
#pragma unroll
      for (int i = 0; i < 4; ++i) {
        const int L = t * 4 + lq;                    // logical 16B slot
        const int ps = (L & 16) | ((L ^ ln) & 15);   // row&15 == ln
        af[i] = *(const bf16x8*)&As[(wm + i * 16 + ln) * 256 + ps * 8];
      }
#pragma unroll
      for (int j = 0; j < 4; ++j)
        bfm[j] = *(const bf16x8*)&Bs[buf * 4096 + (wn + j * 16 + ln) * 32 + lq * 8];

      // all waves done reading this B buffer before tile t+2 overwrites it
      WAIT_LGKM0;
      BARRIER;
      if (t + 2 < 8) ISSUEB(t + 2, buf);

#pragma unroll
      for (int i = 0; i < 4; ++i)
#pragma unroll
        for (int j = 0; j < 4; ++j)
          acc[i][j] = __builtin_amdgcn_mfma_f32_16x16x32_bf16(af[i], bfm[j], acc[i][j], 0, 0, 0);
    }

    // epilogue: C/D layout col=lane&15, row=(lane>>4)*4+reg
#pragma unroll
    for (int j = 0; j < 4; ++j) {
      const int col = bn + wn + j * 16 + ln;
      const float bb = bias[col];
#pragma unroll
      for (int i = 0; i < 4; ++i) {
        const int row0 = bm + wm + i * 16 + lq * 4;
#pragma unroll
        for (int r = 0; r < 4; ++r) {
          const int row = row0 + r;
          if (row < MROWS)
            outp[(size_t)row * NW + col] = f2bf(acc[i][j][r] + bb);
        }
      }
    }
  }
#undef ISSUEB
}

// ---------------------------------------------------------------------------
// Output GEMM -- exact R4 structure (BK=32, pure-gld, proven). A = accb bf16,
// B = Wout^T, f32 out. gy in {2,3} via gybase=2 -> stream1 path.
// ---------------------------------------------------------------------------
template<bool O1BF>
__global__ __launch_bounds__(256) void gemm_pipe(
    const short* __restrict__ A0, const short* __restrict__ A1,
    const short* __restrict__ Bt0, const short* __restrict__ Bt1,
    const float* __restrict__ bias0, const float* __restrict__ bias1,
    short* __restrict__ out0, void* __restrict__ out1v,
    int N1, int gybase)
{
  __shared__ short As[2 * 128 * 32];   // 16 KB (2 buffers)
  __shared__ short Bs[2 * 128 * 32];   // 16 KB

  const int tid = threadIdx.x;
  const int gy = blockIdx.y + gybase;
  const bool sel0 = gy < 2;
  const short* A = sel0 ? A0 : A1;
  const short* Bt = sel0 ? Bt0 : Bt1;
  const float* bias = sel0 ? bias0 : bias1;
  const int bn = (sel0 ? gy : gy - 2) * 128;
  const int bm = blockIdx.x * 128;

  const int wv = tid >> 6;
  const int lane = tid & 63;

  const int srow = lane >> 2;
  const int skel = (lane & 3) * 8;
  const int rA0 = min(bm + wv * 32 + srow, MROWS - 1);       // clamp tail
  const int rA1 = min(bm + wv * 32 + 16 + srow, MROWS - 1);
  const short* gA0 = A + (size_t)rA0 * KD + skel;
  const short* gA1 = A + (size_t)rA1 * KD + skel;
  const short* gB0 = Bt + (size_t)(bn + wv * 32 + srow) * KD + skel;
  const short* gB1 = Bt + (size_t)(bn + wv * 32 + 16 + srow) * KD + skel;
  short* lA0 = &As[(wv * 32) * 32];         // wave-uniform LDS bases
  short* lA1 = &As[(wv * 32 + 16) * 32];
  short* lB0 = &Bs[(wv * 32) * 32];
  short* lB1 = &Bs[(wv * 32 + 16) * 32];

#define ISSUE(t, buf)                          \
  {                                            \
    gld_lds16(gA0 + (t) * 32, lA0 + (buf) * 4096); \
    gld_lds16(gA1 + (t) * 32, lA1 + (buf) * 4096); \
    gld_lds16(gB0 + (t) * 32, lB0 + (buf) * 4096); \
    gld_lds16(gB1 + (t) * 32, lB1 + (buf) * 4096); \
  }

  const int wm = (wv & 1) * 64;
  const int wn = (wv >> 1) * 64;
  const int ln = lane & 15;
  const int lq = lane >> 4;

  f32x4 acc[4][4];
#pragma unroll
  for (int i = 0; i < 4; ++i)
#pragma unroll
    for (int j = 0; j < 4; ++j) acc[i][j] = (f32x4){0.f, 0.f, 0.f, 0.f};

  ISSUE(0, 0);
  ISSUE(1, 1);

#pragma unroll
  for (int t = 0; t < 8; ++t) {
    const int buf = t & 1;
    if (t < 7) { WAIT_VM4; } else { WAIT_VM0; }
    BARRIER;

    bf16x8 af[4], bfm[4];
#pragma unroll
    for (int i = 0; i < 4; ++i)
      af[i] = *(const bf16x8*)&As[buf * 4096 + (wm + i * 16 + ln) * 32 + lq * 8];
#pragma unroll
    for (int j = 0; j < 4; ++j)
      bfm[j] = *(const bf16x8*)&Bs[buf * 4096 + (wn + j * 16 + ln) * 32 + lq * 8];

    WAIT_LGKM0;
    BARRIER;
    if (t + 2 < 8) ISSUE(t + 2, buf);

#pragma unroll
    for (int i = 0; i < 4; ++i)
#pragma unroll
      for (int j = 0; j < 4; ++j)
        acc[i][j] = __builtin_amdgcn_mfma_f32_16x16x32_bf16(af[i], bfm[j], acc[i][j], 0, 0, 0);
  }
#undef ISSUE

  const int N = sel0 ? 256 : N1;
#pragma unroll
  for (int j = 0; j < 4; ++j) {
    const int col = bn + wn + j * 16 + ln;
    const float bb = bias[col];
#pragma unroll
    for (int i = 0; i < 4; ++i) {
      const int row0 = bm + wm + i * 16 + lq * 4;
#pragma unroll
      for (int r = 0; r < 4; ++r) {
        const int row = row0 + r;
        if (row < MROWS) {
          float v = acc[i][j][r] + bb;
          if (sel0)
            out0[(size_t)row * 256 + col] = f2bf(v);
          else if (O1BF)
            ((short*)out1v)[(size_t)row * N + col] = f2bf(v);
          else
            ((float*)out1v)[(size_t)row * N + col] = v;
        }
      }
    }
  }
}

// ---------------------------------------------------------------------------
// Deformable sampling, two-phase, bf16 vproj + bf16 oa.  (UNCHANGED -- at its
// random-line request-throughput floor, 91 us; see rounds 0-5 notes.)
// HARD-WON CONFIG NOTES (rounds 0-5):
//  - NO min-waves clause in __launch_bounds__ (spill trap).
//  - No explicit software pipeline (spill trap).
//  - Occupancy beyond ~13 waves/CU does not help (line-throughput bound).
// vproj: (Lin*B, 256) bf16 rows (pix*B + b), cols h*32+d
// oa: fused bf16 (MROWS, 384): [0,256) offsets, [256,384) attn logits
// ---------------------------------------------------------------------------
__global__ __launch_bounds__(256) void msda_sample(
    const short* __restrict__ vproj, const short* __restrict__ oa,
    const float* __restrict__ refp, short* __restrict__ out)
{
  static constexpr int LVL_H[4] = {100, 50, 25, 13};
  static constexpr int LVL_W[4] = {134, 67, 34, 17};
  static constexpr int LVL_S[4] = {0, 13400, 16750, 17600};

  __shared__ uint4 s_pk[8 * 8 * 17];   // 17,408 B

  const int tid = threadIdx.x;
  const int m0 = blockIdx.x * 8;

  // ---------------- phase 1 ----------------
#pragma unroll
  for (int it = 0; it < 4; ++it) {
    int w = tid + it * 256;
    int mr = w >> 7;
    int rest = w & 127;
    int h = rest >> 4;
    int lp = rest & 15;
    int l = lp >> 2;
    int p = lp & 3;
    int m = m0 + mr;
    if (m < MROWS) {
      int b = m & 1, q = m >> 1;
      const int Hl = LVL_H[l], Wl = LVL_W[l], Sl = LVL_S[l];
      const float fW = (float)Wl, fH = (float)Hl;

      short4 a4 = *(const short4*)(oa + (size_t)m * 384 + 256 + h * 16 + l * 4);
      float a0 = bf2f(a4.x), a1 = bf2f(a4.y), a2 = bf2f(a4.z), a3 = bf2f(a4.w);
      float mx = fmaxf(fmaxf(a0, a1), fmaxf(a2, a3));
      a0 = __expf(a0 - mx); a1 = __expf(a1 - mx);
      a2 = __expf(a2 - mx); a3 = __expf(a3 - mx);
      float sel = (p == 0) ? a0 : (p == 1) ? a1 : (p == 2) ? a2 : a3;
      float aw = sel / (a0 + a1 + a2 + a3);

      const short* oPtr = oa + (size_t)m * 384 + h * 32 + l * 8 + p * 2;
      float ox = bf2f(oPtr[0]), oy = bf2f(oPtr[1]);
      const float* rPtr = refp + ((size_t)b * LQ + q) * 8 + l * 2;
      float rx = rPtr[0], ry = rPtr[1];

      float x = (rx + ox / fW) * fW - 0.5f;
      float y = (ry + oy / fH) * fH - 0.5f;
      float x0f = floorf(x), y0f = floorf(y);
      float dx = x - x0f, dy = y - y0f;
      int x0 = (int)x0f, y0 = (int)y0f;
      int x1 = x0 + 1, y1 = y0 + 1;

      float w00 = (1.f - dx) * (1.f - dy) * aw;
      float w10 = dx * (1.f - dy) * aw;
      float w01 = (1.f - dx) * dy * aw;
      float w11 = dx * dy * aw;

      bool vx0 = (x0 >= 0) & (x0 < Wl);
      bool vx1 = (x1 >= 0) & (x1 < Wl);
      bool vy0 = (y0 >= 0) & (y0 < Hl);
      bool vy1 = (y1 >= 0) & (y1 < Hl);
      int cx0 = min(max(x0, 0), Wl - 1);
      int cx1 = min(max(x1, 0), Wl - 1);
      int cy0 = min(max(y0, 0), Hl - 1);
      int cy1 = min(max(y1, 0), Hl - 1);

      int r0 = Sl + cy0 * Wl;
      int r1 = Sl + cy1 * Wl;

      float f00 = (vy0 & vx0) ? w00 : 0.f;
      float f10 = (vy0 & vx1) ? w10 : 0.f;
      float f01 = (vy1 & vx0) ? w01 : 0.f;
      float f11 = (vy1 & vx1) ? w11 : 0.f;
      u32 pk0 = (u32)((r0 + cx0) * 2 + b) |
                ((u32)__builtin_bit_cast(unsigned short, (_Float16)f00) << 16);
      u32 pk1 = (u32)((r0 + cx1) * 2 + b) |
                ((u32)__builtin_bit_cast(unsigned short, (_Float16)f10) << 16);
      u32 pk2 = (u32)((r1 + cx0) * 2 + b) |
                ((u32)__builtin_bit_cast(unsigned short, (_Float16)f01) << 16);
      u32 pk3 = (u32)((r1 + cx1) * 2 + b) |
                ((u32)__builtin_bit_cast(unsigned short, (_Float16)f11) << 16);
      int e = (mr * 8 + h) * 17 + lp;
      s_pk[e] = make_uint4(pk0, pk1, pk2, pk3);
    }
  }
  __syncthreads();

  // ---------------- phase 2 ----------------
  const int mr = tid >> 5;
  const int t = tid & 31;
  const int h = t >> 2;
  const int dq = t & 3;
  const int m = m0 + mr;
  if (m >= MROWS) return;

  const int laneOff = h * 32 + dq * 8;          // bf16 element offset
  const int ebase = (mr * 8 + h) * 17;
  const short* vp = vproj + laneOff;

  float acc[8];
#pragma unroll
  for (int e = 0; e < 8; ++e) acc[e] = 0.f;

#pragma unroll 4
  for (int lp = 0; lp < 16; ++lp) {
    uint4 pk = s_pk[ebase + lp];
    bf16x8 u00 = *(const bf16x8*)(vp + ((int)(pk.x & 0xFFFFu) << 8));
    bf16x8 u10 = *(const bf16x8*)(vp + ((int)(pk.y & 0xFFFFu) << 8));
    bf16x8 u01 = *(const bf16x8*)(vp + ((int)(pk.z & 0xFFFFu) << 8));
    bf16x8 u11 = *(const bf16x8*)(vp + ((int)(pk.w & 0xFFFFu) << 8));
    float w0 = (float)__builtin_bit_cast(_Float16, (unsigned short)(pk.x >> 16));
    float w1 = (float)__builtin_bit_cast(_Float16, (unsigned short)(pk.y >> 16));
    float w2 = (float)__builtin_bit_cast(_Float16, (unsigned short)(pk.z >> 16));
    float w3 = (float)__builtin_bit_cast(_Float16, (unsigned short)(pk.w >> 16));
#pragma unroll
    for (int e = 0; e < 8; ++e) {
      acc[e] = fmaf(w0, bf2f(u00[e]), acc[e]);
      acc[e] = fmaf(w1, bf2f(u10[e]), acc[e]);
      acc[e] = fmaf(w2, bf2f(u01[e]), acc[e]);
      acc[e] = fmaf(w3, bf2f(u11[e]), acc[e]);
    }
  }

  bf16x8 o;
#pragma unroll
  for (int e = 0; e < 8; ++e) o[e] = f2bf(acc[e]);
  *(bf16x8*)(out + (size_t)m * 256 + laneOff) = o;
}

// ---------------------------------------------------------------------------
extern "C" void kernel_launch(void* const* d_in, const int* in_sizes, int n_in,
                              void* d_out, int out_size, void* d_ws, size_t ws_size,
                              hipStream_t stream)
{
  const float* query = (const float*)d_in[0];   // (Lq, B, 256) fp32
  const float* value = (const float*)d_in[1];   // (Lin, B, 256) fp32
  const float* refp  = (const float*)d_in[2];   // (B, Lq, 4, 2)
  // d_in[3] = spatial_shapes (constant, hardcoded)
  const float* Wv   = (const float*)d_in[4];
  const float* bv   = (const float*)d_in[5];
  const float* Woff = (const float*)d_in[6];
  const float* boff = (const float*)d_in[7];
  const float* Wat  = (const float*)d_in[8];
  const float* bat  = (const float*)d_in[9];
  const float* Wout = (const float*)d_in[10];
  const float* bout = (const float*)d_in[11];
  float* out = (float*)d_out;

  const size_t NELT = (size_t)MROWS * 256;      // 9,124,352
  short* wT    = (short*)d_ws;                  // 229,376 bf16 (4 W^T)
  float* fbias = (float*)(wT + 229376);         // 384 fp32 (boff|bat)
  short* vproj = (short*)(fbias + 384);         // NELT bf16
  short* oa    = vproj + NELT;                  // MROWS*384 bf16
  short* accb  = oa + (size_t)MROWS * 384;      // NELT bf16

  dim3 blk(256, 1, 1);
  int gm = (MROWS + 127) / 128;   // 279

  // tiny: W transposes + fused bias
  prep_w<<<dim3(898), blk, 0, stream>>>(Wv, Woff, Wat, Wout, boff, bat, wT, fbias);

  // fused input GEMMs: A staged once per block (fp32->bf16 in-staging),
  // all N-stripes computed per A-load. s=0: value->vproj; s=1: query->oa.
  gemm_fused_in<<<dim3(gm, 2), blk, 0, stream>>>(
      value, query, wT, bv, fbias, vproj, oa);

  msda_sample<<<dim3((MROWS + 7) / 8), blk, 0, stream>>>(vproj, oa, refp, accb);

  // output GEMM: R4 structure, bf16 A (accb), f32 out
  gemm_pipe<false><<<dim3(gm, 2), blk, 0, stream>>>(
      accb, accb, wT + 163840, wT + 163840, bout, bout, nullptr, out, 256, 2);
}

// Round 11
// 272.292 us; speedup vs baseline: 1.5656x; 1.0680x over previous
//
#include <hip/hip_runtime.h>
#include <math.h>

// Problem constants (fixed by setup_inputs)
#define LQ    17821
#define MROWS 35642     // Lq * B
#define KD    256

typedef __attribute__((ext_vector_type(8))) short bf16x8;   // 8 bf16 = 4 VGPRs
typedef __attribute__((ext_vector_type(4))) float f32x4;
typedef unsigned int u32;

__device__ __forceinline__ short f2bf(float f) {
  union { float f; unsigned u; } c; c.f = f;
  unsigned u = c.u;
  return (short)((u + 0x7fffu + ((u >> 16) & 1u)) >> 16);   // RNE
}
__device__ __forceinline__ float bf2f(short s) {
  union { unsigned u; float f; } c;
  c.u = ((unsigned)(unsigned short)s) << 16;
  return c.f;
}

// async global->LDS, 16 B per lane: LDS dest = wave-uniform base + lane*16
__device__ __forceinline__ void gld_lds16(const short* g, short* l) {
  __builtin_amdgcn_global_load_lds(
      (const __attribute__((address_space(1))) u32*)g,
      (__attribute__((address_space(3))) u32*)l, 16, 0, 0);
}

// s_waitcnt immediates (gfx9 encoding: vm[3:0]|[15:14], exp[6:4], lgkm[11:8])
#define WAIT_VM4   { __builtin_amdgcn_s_waitcnt(0x0F74); asm volatile("" ::: "memory"); }
#define WAIT_VM0   { __builtin_amdgcn_s_waitcnt(0x0F70); asm volatile("" ::: "memory"); }
#define WAIT_LGKM0 { __builtin_amdgcn_s_waitcnt(0xC07F); asm volatile("" ::: "memory"); }
#define BARRIER    { asm volatile("" ::: "memory"); __builtin_amdgcn_s_barrier(); asm volatile("" ::: "memory"); }

// ---------------------------------------------------------------------------
// prep: y=0 -> query fp32->bf16; y=1 -> value fp32->bf16;
//       y=2 -> all 4 W^T bf16 transposes + fused bias (first ~898 blocks).
// (R4 structure -- R10 showed the "A-once" fusion regresses: the stripe
// re-reads it eliminated were already L3-hits, and it lost block parallelism.)
// wT layout: [0,65536) Wv^T | [65536,131072) Woff^T | [131072,163840) Wat^T |
//            [163840,229376) Wout^T   (each W^T is (N x 256) row-major)
// ---------------------------------------------------------------------------
__global__ __launch_bounds__(256) void prep(
    const float* __restrict__ query, const float* __restrict__ value,
    const float* __restrict__ Wv, const float* __restrict__ Woff,
    const float* __restrict__ Wat, const float* __restrict__ Wout,
    const float* __restrict__ boff, const float* __restrict__ bat,
    short* __restrict__ qb, short* __restrict__ vb,
    short* __restrict__ wT, float* __restrict__ fbias)
{
  const int y = blockIdx.y;
  if (y < 2) {
    const float* s = y ? value : query;
    short* d = y ? vb : qb;
    int i = (blockIdx.x * 256 + threadIdx.x) * 4;
    if (i < MROWS * KD) {
      float4 x = *(const float4*)(s + i);
      short4 o;
      o.x = f2bf(x.x); o.y = f2bf(x.y); o.z = f2bf(x.z); o.w = f2bf(x.w);
      *(short4*)(d + i) = o;
    }
    return;
  }
  int idx = blockIdx.x * 256 + threadIdx.x;
  if (idx < 229376) {
    const float* W; int base, N;
    if (idx < 65536)       { W = Wv;   base = 0;      N = 256; }
    else if (idx < 131072) { W = Woff; base = 65536;  N = 256; }
    else if (idx < 163840) { W = Wat;  base = 131072; N = 128; }
    else                   { W = Wout; base = 163840; N = 256; }
    int local = idx - base;
    int n = local >> 8, k = local & 255;
    wT[idx] = f2bf(W[k * N + n]);
  } else if (idx < 229376 + 384) {
    int j = idx - 229376;
    fbias[j] = (j < 256) ? boff[j] : bat[j - 256];
  }
}

// ---------------------------------------------------------------------------
// Pipelined bf16 MFMA GEMM -- R11: exact R4 K-loop (BK=32, pure-gld, proven
// fastest) + LDS-COALESCED bf16 EPILOGUE.
//
// R9-probe evidence for the epilogue fix: gemm WRITE_SIZE was 2x the write
// demand and FETCH_SIZE ~= the write demand. Cause: the C/D fragment layout
// (row = lq*4+r) makes bf16 stores 2 B/lane scattered over 4 rows -> each
// 64 B output line is filled by separate 32 B segments -> write-allocate
// fetches every line AND evicts half-lines twice. Fix: route acc through the
// (dead-after-K-loop) staging LDS, transposed, then store bf16x8 per lane --
// 16 lanes x 16 B = 256 B/row contiguous, full-line writes. Values are
// bit-identical (same f2bf(acc+bb)); only the store path changes.
// LDS epilogue tile: [64][132] shorts (stride 132 -> lq-rows 8 banks apart,
// conflict-free scalar writes; 16.9 KB, fits the 32 KB smem).
// f32 output path (gemm2) keeps direct stores (already 64 B-coalesced).
//
// 128x128 tile, 4 waves, BK=32, K=256 -> 8 tiles, 2-deep gld double-buffer,
// counted vmcnt(4) (never 0 mid-loop). Pure-gld staging (R7 lesson).
// LAUNCH_BOUNDS: plain (256) (rounds 2-5: min-waves clauses cause spill).
// ---------------------------------------------------------------------------
template<bool O1BF>
__global__ __launch_bounds__(256) void gemm_pipe(
    const short* __restrict__ A0, const short* __restrict__ A1,
    const short* __restrict__ Bt0, const short* __restrict__ Bt1,
    const float* __restrict__ bias0, const float* __restrict__ bias1,
    short* __restrict__ out0, void* __restrict__ out1v,
    int N1, int gybase)
{
  __shared__ short smem[16384];        // 32 KB: As | Bs staging, then epilogue
  short* As = smem;                    // 2 x 128 x 32 (16 KB)
  short* Bs = smem + 8192;             // 2 x 128 x 32 (16 KB)

  const int tid = threadIdx.x;
  const int gy = blockIdx.y + gybase;
  const bool sel0 = gy < 2;
  const short* A = sel0 ? A0 : A1;
  const short* Bt = sel0 ? Bt0 : Bt1;
  const float* bias = sel0 ? bias0 : bias1;
  const int bn = (sel0 ? gy : gy - 2) * 128;
  const int bm = blockIdx.x * 128;

  const int wv = tid >> 6;
  const int lane = tid & 63;

  // staging: wave wv stages rows [wv*32, wv*32+32) of A and B, two 16-row
  // segments each; lane covers (row = lane/4, kseg = lane%4)
  const int srow = lane >> 2;
  const int skel = (lane & 3) * 8;
  const int rA0 = min(bm + wv * 32 + srow, MROWS - 1);       // clamp tail
  const int rA1 = min(bm + wv * 32 + 16 + srow, MROWS - 1);
  const short* gA0 = A + (size_t)rA0 * KD + skel;
  const short* gA1 = A + (size_t)rA1 * KD + skel;
  const short* gB0 = Bt + (size_t)(bn + wv * 32 + srow) * KD + skel;
  const short* gB1 = Bt + (size_t)(bn + wv * 32 + 16 + srow) * KD + skel;
  short* lA0 = &As[(wv * 32) * 32];         // wave-uniform LDS bases
  short* lA1 = &As[(wv * 32 + 16) * 32];
  short* lB0 = &Bs[(wv * 32) * 32];
  short* lB1 = &Bs[(wv * 32 + 16) * 32];

#define ISSUE(t, buf)                          \
  {                                            \
    gld_lds16(gA0 + (t) * 32, lA0 + (buf) * 4096); \
    gld_lds16(gA1 + (t) * 32, lA1 + (buf) * 4096); \
    gld_lds16(gB0 + (t) * 32, lB0 + (buf) * 4096); \
    gld_lds16(gB1 + (t) * 32, lB1 + (buf) * 4096); \
  }

  const int wm = (wv & 1) * 64;
  const int wn = (wv >> 1) * 64;
  const int ln = lane & 15;
  const int lq = lane >> 4;

  f32x4 acc[4][4];
#pragma unroll
  for (int i = 0; i < 4; ++i)
#pragma unroll
    for (int j = 0; j < 4; ++j) acc[i][j] = (f32x4){0.f, 0.f, 0.f, 0.f};

  ISSUE(0, 0);
  ISSUE(1, 1);

#pragma unroll
  for (int t = 0; t < 8; ++t) {
    const int buf = t & 1;
    // tile t landed; tile t+1 (if any) stays in flight
    if (t < 7) { WAIT_VM4; } else { WAIT_VM0; }
    BARRIER;

    bf16x8 af[4], bfm[4];
#pragma unroll
    for (int i = 0; i < 4; ++i)
      af[i] = *(const bf16x8*)&As[buf * 4096 + (wm + i * 16 + ln) * 32 + lq * 8];
#pragma unroll
    for (int j = 0; j < 4; ++j)
      bfm[j] = *(const bf16x8*)&Bs[buf * 4096 + (wn + j * 16 + ln) * 32 + lq * 8];

    // all waves done reading this buffer before tile t+2 overwrites it
    WAIT_LGKM0;
    BARRIER;
    if (t + 2 < 8) ISSUE(t + 2, buf);

#pragma unroll
    for (int i = 0; i < 4; ++i)
#pragma unroll
      for (int j = 0; j < 4; ++j)
        acc[i][j] = __builtin_amdgcn_mfma_f32_16x16x32_bf16(af[i], bfm[j], acc[i][j], 0, 0, 0);
  }
#undef ISSUE

  // ---- epilogue: C/D layout col=lane&15, row=(lane>>4)*4+reg ----
  const int N = sel0 ? 256 : N1;

  if (!sel0 && !O1BF) {
    // f32 output (gemm2): direct stores -- 16 consecutive f32 per (i,j,lq)
    // group = 64 B aligned segments, already coalesced.
#pragma unroll
    for (int j = 0; j < 4; ++j) {
      const int col = bn + wn + j * 16 + ln;
      const float bb = bias[col];
#pragma unroll
      for (int i = 0; i < 4; ++i) {
        const int row0 = bm + wm + i * 16 + lq * 4;
#pragma unroll
        for (int r = 0; r < 4; ++r) {
          const int row = row0 + r;
          if (row < MROWS)
            ((float*)out1v)[(size_t)row * N + col] = acc[i][j][r] + bb;
        }
      }
    }
    return;
  }

  // bf16 output: LDS-transposed coalesced stores (smem is dead post-K-loop).
  // Tile half h holds rows [h*64, h*64+64); owned by waves with (wv&1)==h.
  short* outb = sel0 ? out0 : (short*)out1v;
#pragma unroll
  for (int h = 0; h < 2; ++h) {
    BARRIER;   // smem free (K-loop drained / previous half's reads done)
    if ((wv & 1) == h) {
#pragma unroll
      for (int j = 0; j < 4; ++j) {
        const int col = wn + j * 16 + ln;
        const float bb = bias[bn + col];
#pragma unroll
        for (int i = 0; i < 4; ++i) {
          const int rl = i * 16 + lq * 4;
#pragma unroll
          for (int r = 0; r < 4; ++r)
            smem[(rl + r) * 132 + col] = f2bf(acc[i][j][r] + bb);
        }
      }
    }
    BARRIER;
    // store half h: 64 rows x 128 cols bf16; 256 thr x 4 iters x 16 B;
    // 16 lanes cover 256 B contiguous per row -> full-line writes.
#pragma unroll
    for (int p = 0; p < 4; ++p) {
      const int idx = tid + p * 256;        // 0..1023
      const int rl = idx >> 4;              // 0..63
      const int cg = idx & 15;              // 16-B col group
      const int grow = bm + h * 64 + rl;
      if (grow < MROWS)
        *(bf16x8*)(outb + (size_t)grow * N + bn + cg * 8) =
            *(const bf16x8*)&smem[rl * 132 + cg * 8];
    }
  }
}

// ---------------------------------------------------------------------------
// Deformable sampling, two-phase, bf16 vproj + bf16 oa.  (UNCHANGED -- at its
// random-line request-throughput floor, 91 us; see rounds 0-5 notes.)
// HARD-WON CONFIG NOTES (rounds 0-5):
//  - NO min-waves clause in __launch_bounds__ (spill trap).
//  - No explicit software pipeline (spill trap).
//  - Occupancy beyond ~13 waves/CU does not help (line-throughput bound).
// vproj: (Lin*B, 256) bf16 rows (pix*B + b), cols h*32+d
// oa: fused bf16 (MROWS, 384): [0,256) offsets, [256,384) attn logits
// ---------------------------------------------------------------------------
__global__ __launch_bounds__(256) void msda_sample(
    const short* __restrict__ vproj, const short* __restrict__ oa,
    const float* __restrict__ refp, short* __restrict__ out)
{
  static constexpr int LVL_H[4] = {100, 50, 25, 13};
  static constexpr int LVL_W[4] = {134, 67, 34, 17};
  static constexpr int LVL_S[4] = {0, 13400, 16750, 17600};

  __shared__ uint4 s_pk[8 * 8 * 17];   // 17,408 B

  const int tid = threadIdx.x;
  const int m0 = blockIdx.x * 8;

  // ---------------- phase 1 ----------------
#pragma unroll
  for (int it = 0; it < 4; ++it) {
    int w = tid + it * 256;
    int mr = w >> 7;
    int rest = w & 127;
    int h = rest >> 4;
    int lp = rest & 15;
    int l = lp >> 2;
    int p = lp & 3;
    int m = m0 + mr;
    if (m < MROWS) {
      int b = m & 1, q = m >> 1;
      const int Hl = LVL_H[l], Wl = LVL_W[l], Sl = LVL_S[l];
      const float fW = (float)Wl, fH = (float)Hl;

      short4 a4 = *(const short4*)(oa + (size_t)m * 384 + 256 + h * 16 + l * 4);
      float a0 = bf2f(a4.x), a1 = bf2f(a4.y), a2 = bf2f(a4.z), a3 = bf2f(a4.w);
      float mx = fmaxf(fmaxf(a0, a1), fmaxf(a2, a3));
      a0 = __expf(a0 - mx); a1 = __expf(a1 - mx);
      a2 = __expf(a2 - mx); a3 = __expf(a3 - mx);
      float sel = (p == 0) ? a0 : (p == 1) ? a1 : (p == 2) ? a2 : a3;
      float aw = sel / (a0 + a1 + a2 + a3);

      const short* oPtr = oa + (size_t)m * 384 + h * 32 + l * 8 + p * 2;
      float ox = bf2f(oPtr[0]), oy = bf2f(oPtr[1]);
      const float* rPtr = refp + ((size_t)b * LQ + q) * 8 + l * 2;
      float rx = rPtr[0], ry = rPtr[1];

      float x = (rx + ox / fW) * fW - 0.5f;
      float y = (ry + oy / fH) * fH - 0.5f;
      float x0f = floorf(x), y0f = floorf(y);
      float dx = x - x0f, dy = y - y0f;
      int x0 = (int)x0f, y0 = (int)y0f;
      int x1 = x0 + 1, y1 = y0 + 1;

      float w00 = (1.f - dx) * (1.f - dy) * aw;
      float w10 = dx * (1.f - dy) * aw;
      float w01 = (1.f - dx) * dy * aw;
      float w11 = dx * dy * aw;

      bool vx0 = (x0 >= 0) & (x0 < Wl);
      bool vx1 = (x1 >= 0) & (x1 < Wl);
      bool vy0 = (y0 >= 0) & (y0 < Hl);
      bool vy1 = (y1 >= 0) & (y1 < Hl);
      int cx0 = min(max(x0, 0), Wl - 1);
      int cx1 = min(max(x1, 0), Wl - 1);
      int cy0 = min(max(y0, 0), Hl - 1);
      int cy1 = min(max(y1, 0), Hl - 1);

      int r0 = Sl + cy0 * Wl;
      int r1 = Sl + cy1 * Wl;

      float f00 = (vy0 & vx0) ? w00 : 0.f;
      float f10 = (vy0 & vx1) ? w10 : 0.f;
      float f01 = (vy1 & vx0) ? w01 : 0.f;
      float f11 = (vy1 & vx1) ? w11 : 0.f;
      u32 pk0 = (u32)((r0 + cx0) * 2 + b) |
                ((u32)__builtin_bit_cast(unsigned short, (_Float16)f00) << 16);
      u32 pk1 = (u32)((r0 + cx1) * 2 + b) |
                ((u32)__builtin_bit_cast(unsigned short, (_Float16)f10) << 16);
      u32 pk2 = (u32)((r1 + cx0) * 2 + b) |
                ((u32)__builtin_bit_cast(unsigned short, (_Float16)f01) << 16);
      u32 pk3 = (u32)((r1 + cx1) * 2 + b) |
                ((u32)__builtin_bit_cast(unsigned short, (_Float16)f11) << 16);
      int e = (mr * 8 + h) * 17 + lp;
      s_pk[e] = make_uint4(pk0, pk1, pk2, pk3);
    }
  }
  __syncthreads();

  // ---------------- phase 2 ----------------
  const int mr = tid >> 5;
  const int t = tid & 31;
  const int h = t >> 2;
  const int dq = t & 3;
  const int m = m0 + mr;
  if (m >= MROWS) return;

  const int laneOff = h * 32 + dq * 8;          // bf16 element offset
  const int ebase = (mr * 8 + h) * 17;
  const short* vp = vproj + laneOff;

  float acc[8];
#pragma unroll
  for (int e = 0; e < 8; ++e) acc[e] = 0.f;

#pragma unroll 4
  for (int lp = 0; lp < 16; ++lp) {
    uint4 pk = s_pk[ebase + lp];
    bf16x8 u00 = *(const bf16x8*)(vp + ((int)(pk.x & 0xFFFFu) << 8));
    bf16x8 u10 = *(const bf16x8*)(vp + ((int)(pk.y & 0xFFFFu) << 8));
    bf16x8 u01 = *(const bf16x8*)(vp + ((int)(pk.z & 0xFFFFu) << 8));
    bf16x8 u11 = *(const bf16x8*)(vp + ((int)(pk.w & 0xFFFFu) << 8));
    float w0 = (float)__builtin_bit_cast(_Float16, (unsigned short)(pk.x >> 16));
    float w1 = (float)__builtin_bit_cast(_Float16, (unsigned short)(pk.y >> 16));
    float w2 = (float)__builtin_bit_cast(_Float16, (unsigned short)(pk.z >> 16));
    float w3 = (float)__builtin_bit_cast(_Float16, (unsigned short)(pk.w >> 16));
#pragma unroll
    for (int e = 0; e < 8; ++e) {
      acc[e] = fmaf(w0, bf2f(u00[e]), acc[e]);
      acc[e] = fmaf(w1, bf2f(u10[e]), acc[e]);
      acc[e] = fmaf(w2, bf2f(u01[e]), acc[e]);
      acc[e] = fmaf(w3, bf2f(u11[e]), acc[e]);
    }
  }

  bf16x8 o;
#pragma unroll
  for (int e = 0; e < 8; ++e) o[e] = f2bf(acc[e]);
  *(bf16x8*)(out + (size_t)m * 256 + laneOff) = o;
}

// ---------------------------------------------------------------------------
extern "C" void kernel_launch(void* const* d_in, const int* in_sizes, int n_in,
                              void* d_out, int out_size, void* d_ws, size_t ws_size,
                              hipStream_t stream)
{
  const float* query = (const float*)d_in[0];   // (Lq, B, 256)
  const float* value = (const float*)d_in[1];   // (Lin, B, 256)
  const float* refp  = (const float*)d_in[2];   // (B, Lq, 4, 2)
  // d_in[3] = spatial_shapes (constant, hardcoded)
  const float* Wv   = (const float*)d_in[4];
  const float* bv   = (const float*)d_in[5];
  const float* Woff = (const float*)d_in[6];
  const float* boff = (const float*)d_in[7];
  const float* Wat  = (const float*)d_in[8];
  const float* bat  = (const float*)d_in[9];
  const float* Wout = (const float*)d_in[10];
  const float* bout = (const float*)d_in[11];
  float* out = (float*)d_out;

  const size_t NELT = (size_t)MROWS * 256;      // 9,124,352
  short* wT    = (short*)d_ws;                  // 229,376 bf16 (4 W^T)
  float* fbias = (float*)(wT + 229376);         // 384 fp32 (boff|bat)
  short* qb    = (short*)(fbias + 384);         // NELT bf16
  short* vb    = qb + NELT;                     // NELT bf16 (reused as accb)
  short* vproj = vb + NELT;                     // NELT bf16
  short* oa    = vproj + NELT;                  // MROWS*384 bf16
  short* accb  = vb;                            // alias (vb dead after GEMM)

  dim3 blk(256, 1, 1);
  int gm = (MROWS + 127) / 128;   // 279

  prep<<<dim3(8911, 3), blk, 0, stream>>>(
      query, value, Wv, Woff, Wat, Wout, boff, bat, qb, vb, wT, fbias);

  // fused: gy 0-1 = value-proj (bf16 out0), gy 2-4 = offset+attn (bf16 out1)
  gemm_pipe<true><<<dim3(gm, 5), blk, 0, stream>>>(
      vb, qb, wT, wT + 65536, bv, fbias, vproj, oa, 384, 0);

  msda_sample<<<dim3((MROWS + 7) / 8), blk, 0, stream>>>(vproj, oa, refp, accb);

  // output GEMM: stream1 path, f32 out = d_out, N=256
  gemm_pipe<false><<<dim3(gm, 2), blk, 0, stream>>>(
      accb, accb, wT + 163840, wT + 163840, bout, bout, nullptr, out, 256, 2);
}